// Round 1
// baseline (3477.559 us; speedup 1.0000x reference)
//
#include <hip/hip_runtime.h>
#include <cstdint>

#define T_LEN 4096
#define S_DIM 308
#define S_PAD 320
#define E_DIM 126
#define NBATCH 32
#define NPAIR 160     // S_PAD/2 f16 pairs
#define NC 3          // k-split factor
#define PPC 52        // pairs per c-chunk
#define KCH 104       // k per c-chunk

typedef _Float16 h2 __attribute__((ext_vector_type(2)));
union U32H2 { uint32_t u; h2 h; };

__device__ __forceinline__ float fdot2u(uint32_t a, uint32_t b, float c) {
  U32H2 ua; ua.u = a; U32H2 ub; ub.u = b;
#if __has_builtin(__builtin_amdgcn_fdot2)
  return __builtin_amdgcn_fdot2(ua.h, ub.h, c, false);
#else
  return c + (float)ua.h.x * (float)ub.h.x + (float)ua.h.y * (float)ub.h.y;
#endif
}

// ---- kernel 0a: pack A[k][j] (fp32, row-major) into f16 k-pairs, layout [c][p][j] ----
__global__ __launch_bounds__(320) void pack_A(const float* __restrict__ A, uint32_t* __restrict__ Apack) {
  int bx = blockIdx.x;            // 0..155 = c*PPC + p
  int c = bx / PPC, p = bx % PPC;
  int j = threadIdx.x;            // 0..319
  int k0 = c * KCH + 2 * p, k1 = k0 + 1;
  float a0 = (k0 < S_DIM && j < S_DIM) ? A[k0 * S_DIM + j] : 0.f;
  float a1 = (k1 < S_DIM && j < S_DIM) ? A[k1 * S_DIM + j] : 0.f;
  U32H2 u; u.h.x = (_Float16)a0; u.h.y = (_Float16)a1;
  Apack[(size_t)bx * S_PAD + j] = u.u;
}

// ---- kernel 0b: Bt[e][j] = B[j][e], j padded to 320 with zeros ----
__global__ __launch_bounds__(320) void transpose_B(const float* __restrict__ Bm, float* __restrict__ Bt) {
  int e = blockIdx.x;             // 0..125
  int j = threadIdx.x;            // 0..319
  Bt[(size_t)e * S_PAD + j] = (j < S_DIM) ? Bm[j * E_DIM + e] : 0.f;
}

// ---- kernel 1: emis[b,t,s] = sum_e inputs[b,t,e]*B[s,e], stored as f16 s-pairs ----
__global__ __launch_bounds__(320) void emis_kernel(const float* __restrict__ inp,
                                                   const float* __restrict__ Bt,
                                                   uint32_t* __restrict__ emisPack) {
  __shared__ float inL[32 * E_DIM];
  int b = blockIdx.x, tc = blockIdx.y;
  int tid = threadIdx.x;
  int p = tid % NPAIR, half = tid / NPAIR;   // p: s-pair, half: which 16 t's
  int t0 = tc * 32;
  const float* src = inp + ((size_t)b * T_LEN + t0) * E_DIM;
  for (int idx = tid; idx < 32 * E_DIM; idx += 320) inL[idx] = src[idx];
  __syncthreads();
  float acc0[16], acc1[16];
#pragma unroll
  for (int i = 0; i < 16; i++) { acc0[i] = 0.f; acc1[i] = 0.f; }
  const float* inbase = inL + half * 16 * E_DIM;
  for (int e = 0; e < E_DIM; e++) {
    float2 bb = ((const float2*)(Bt + (size_t)e * S_PAD))[p];
#pragma unroll
    for (int tt = 0; tt < 16; tt++) {
      float v = inbase[tt * E_DIM + e];
      acc0[tt] += bb.x * v;
      acc1[tt] += bb.y * v;
    }
  }
#pragma unroll
  for (int tt = 0; tt < 16; tt++) {
    U32H2 u; u.h.x = (_Float16)acc0[tt]; u.h.y = (_Float16)acc1[tt];
    emisPack[((size_t)b * T_LEN + t0 + half * 16 + tt) * NPAIR + p] = u.u;
  }
}

// ---- kernel 2: sequential alpha recursion, one block per batch ----
// thread (j = tid%320, c = tid/320). A f16-pairs register-resident (52 dwords).
// alpha kept in LDS as f16 pairs; exact power-of-2 (x128) scaling each step,
// exact renorm every 8 steps; loglik telescopes.
__global__ __launch_bounds__(960) void hmm_forward(const uint32_t* __restrict__ Apack,
                                                   const uint32_t* __restrict__ emisPack,
                                                   const float* __restrict__ Ivec,
                                                   float* __restrict__ out) {
  __shared__ alignas(16) uint32_t alphaPair[NPAIR];
  __shared__ float part[NC * S_PAD];
  __shared__ uint32_t eBuf[3][NPAIR];
  __shared__ float zslot[8];
  int b = blockIdx.x;
  int tid = threadIdx.x;
  int j = tid % S_PAD, c = tid / S_PAD;

  // load A fragment into registers (coalesced in j)
  uint32_t areg[PPC];
  {
    const uint32_t* ap = Apack + (size_t)c * PPC * S_PAD + j;
#pragma unroll
    for (int p2 = 0; p2 < PPC; p2++) areg[p2] = ap[p2 * S_PAD];
  }
  const uint32_t* eb = emisPack + (size_t)b * T_LEN * NPAIR;

  // t = 0: stored = I * e0 * 128  (scaled so f16 entries stay in normal range)
  if (c == 0) {
    float Ij = (j < S_DIM) ? Ivec[j] : 0.f;
    U32H2 ue; ue.u = eb[j >> 1];
    float e0 = (j & 1) ? (float)ue.h.y : (float)ue.h.x;
    ((_Float16*)alphaPair)[j] = (_Float16)(Ij * e0 * 128.f);
  }
  // emission prefetch pipeline (c2 group owns it)
  uint32_t evA = 0, evB = 0;
  if (c == 2 && j < NPAIR) {
    eBuf[1][j] = eb[1 * NPAIR + j];
    evA = eb[2 * NPAIR + j];
    evB = eb[3 * NPAIR + j];
  }
  float ll = 0.f;
  __syncthreads();

  for (int t = 1; t < T_LEN; t++) {
    // rolling emission prefetch: write slot t+1 (3-step-old load), issue t+3
    if (c == 2 && j < NPAIR) {
      eBuf[(t + 1) % 3][j] = evA;
      evA = evB;
      int tn = t + 3; if (tn > T_LEN - 1) tn = T_LEN - 1;
      evB = eb[(size_t)tn * NPAIR + j];
    }
    // partial dot: acc = sum over this thread's k-chunk of alpha[k]*A[k][j]
    float acc = 0.f;
    const uint4* apv = (const uint4*)(alphaPair + c * PPC);
#pragma unroll
    for (int i = 0; i < 13; i++) {
      uint4 q = apv[i];
      acc = fdot2u(areg[4 * i + 0], q.x, acc);
      acc = fdot2u(areg[4 * i + 1], q.y, acc);
      acc = fdot2u(areg[4 * i + 2], q.z, acc);
      acc = fdot2u(areg[4 * i + 3], q.w, acc);
    }
    part[c * S_PAD + j] = acc;
    bool renorm = ((t & 7) == 0) || (t == T_LEN - 1);
    __syncthreads();

    float s = 0.f;
    if (c == 0) {
      s = part[j] + part[S_PAD + j] + part[2 * S_PAD + j];
      _Float16 ehv = ((_Float16*)(eBuf[t % 3]))[j];   // 0 for pad j
      s = s * (float)ehv * 128.f;
      if (renorm) {
        float w = s;
#pragma unroll
        for (int off = 32; off >= 1; off >>= 1) w += __shfl_xor(w, off);
        if ((j & 63) == 0) zslot[j >> 6] = w;
      }
    }
    if (renorm) {
      __syncthreads();
      if (c == 0) {
        float m = zslot[0] + zslot[1] + zslot[2] + zslot[3] + zslot[4];
        if (tid == 0) ll += logf(m);
        s /= m;
      }
    }
    if (c == 0) ((_Float16*)alphaPair)[j] = (_Float16)s;
    __syncthreads();
  }
  // ll_total = sum(log m) - 4096*ln(128)  (4095 loop scalings + 1 init scaling)
  if (tid == 0) out[b] = ll - 19873.9159610148f;
}

extern "C" void kernel_launch(void* const* d_in, const int* in_sizes, int n_in,
                              void* d_out, int out_size, void* d_ws, size_t ws_size,
                              hipStream_t stream) {
  const float* inp = (const float*)d_in[0];   // [32,4096,126]
  const float* A   = (const float*)d_in[1];   // [308,308]
  const float* Bm  = (const float*)d_in[2];   // [308,126]
  const float* Iv  = (const float*)d_in[3];   // [308]
  float* out = (float*)d_out;                 // [32]

  uint8_t* ws = (uint8_t*)d_ws;
  uint32_t* Apack    = (uint32_t*)(ws);                 // 156*320*4   = 199,680 B
  float*    Bt       = (float*)(ws + (256u << 10));     // 126*320*4   = 161,280 B
  uint32_t* emisPack = (uint32_t*)(ws + (512u << 10));  // 32*4096*160*4 = 83,886,080 B

  hipLaunchKernelGGL(pack_A,      dim3(NC * PPC), dim3(320), 0, stream, A, Apack);
  hipLaunchKernelGGL(transpose_B, dim3(E_DIM),    dim3(320), 0, stream, Bm, Bt);
  hipLaunchKernelGGL(emis_kernel, dim3(NBATCH, T_LEN / 32), dim3(320), 0, stream, inp, Bt, emisPack);
  hipLaunchKernelGGL(hmm_forward, dim3(NBATCH),   dim3(960), 0, stream, Apack, emisPack, Iv, out);
}

// Round 2
// 686.807 us; speedup vs baseline: 5.0634x; 5.0634x over previous
//
#include <hip/hip_runtime.h>
#include <cstdint>

#define T_LEN 4096
#define S_DIM 308
#define S_PAD 320
#define E_DIM 126
#define NBATCH 32
#define NPAIR 160     // S_PAD/2 f16 pairs
#define NC 3          // k-split factor
#define PPC 52        // pairs per c-chunk
#define KCH 104       // k per c-chunk
#define NCHUNK 8      // time chunks per batch
#define CHL 512       // accounted steps per chunk
#define WARM 16       // warm-up steps (contraction ~0.03/step -> 1e-24)

typedef _Float16 h2 __attribute__((ext_vector_type(2)));
union U32H2 { uint32_t u; h2 h; };

__device__ __forceinline__ float fdot2u(uint32_t a, uint32_t b, float c) {
  U32H2 ua; ua.u = a; U32H2 ub; ub.u = b;
#if __has_builtin(__builtin_amdgcn_fdot2)
  return __builtin_amdgcn_fdot2(ua.h, ub.h, c, false);
#else
  return c + (float)ua.h.x * (float)ub.h.x + (float)ua.h.y * (float)ub.h.y;
#endif
}

// ---- kernel 0a: pack A[k][j] (fp32, row-major) into f16 k-pairs, layout [c][p][j] ----
__global__ __launch_bounds__(320) void pack_A(const float* __restrict__ A, uint32_t* __restrict__ Apack) {
  int bx = blockIdx.x;            // 0..155 = c*PPC + p
  int c = bx / PPC, p = bx % PPC;
  int j = threadIdx.x;            // 0..319
  int k0 = c * KCH + 2 * p, k1 = k0 + 1;
  float a0 = (k0 < S_DIM && j < S_DIM) ? A[k0 * S_DIM + j] : 0.f;
  float a1 = (k1 < S_DIM && j < S_DIM) ? A[k1 * S_DIM + j] : 0.f;
  U32H2 u; u.h.x = (_Float16)a0; u.h.y = (_Float16)a1;
  Apack[(size_t)bx * S_PAD + j] = u.u;
}

// ---- kernel 0b: Bt[e][j] = B[j][e], j padded to 320 with zeros ----
__global__ __launch_bounds__(320) void transpose_B(const float* __restrict__ Bm, float* __restrict__ Bt) {
  int e = blockIdx.x;             // 0..125
  int j = threadIdx.x;            // 0..319
  Bt[(size_t)e * S_PAD + j] = (j < S_DIM) ? Bm[j * E_DIM + e] : 0.f;
}

// ---- kernel 0c: zero the output (re-poisoned 0xAA before every launch) ----
__global__ void zero_out(float* __restrict__ out) {
  if (threadIdx.x < NBATCH) out[threadIdx.x] = 0.f;
}

// ---- kernel 1: emis[b,t,s] = sum_e inputs[b,t,e]*B[s,e], stored as f16 s-pairs ----
__global__ __launch_bounds__(320) void emis_kernel(const float* __restrict__ inp,
                                                   const float* __restrict__ Bt,
                                                   uint32_t* __restrict__ emisPack) {
  __shared__ float inL[32 * E_DIM];
  int b = blockIdx.x, tc = blockIdx.y;
  int tid = threadIdx.x;
  int p = tid % NPAIR, half = tid / NPAIR;   // p: s-pair, half: which 16 t's
  int t0 = tc * 32;
  const float* src = inp + ((size_t)b * T_LEN + t0) * E_DIM;
  for (int idx = tid; idx < 32 * E_DIM; idx += 320) inL[idx] = src[idx];
  __syncthreads();
  float acc0[16], acc1[16];
#pragma unroll
  for (int i = 0; i < 16; i++) { acc0[i] = 0.f; acc1[i] = 0.f; }
  const float* inbase = inL + half * 16 * E_DIM;
  for (int e = 0; e < E_DIM; e++) {
    float2 bb = ((const float2*)(Bt + (size_t)e * S_PAD))[p];
#pragma unroll
    for (int tt = 0; tt < 16; tt++) {
      float v = inbase[tt * E_DIM + e];
      acc0[tt] += bb.x * v;
      acc1[tt] += bb.y * v;
    }
  }
#pragma unroll
  for (int tt = 0; tt < 16; tt++) {
    U32H2 u; u.h.x = (_Float16)acc0[tt]; u.h.y = (_Float16)acc1[tt];
    emisPack[((size_t)b * T_LEN + t0 + half * 16 + tt) * NPAIR + p] = u.u;
  }
}

// ---- kernel 2: chunked alpha recursion, one block per (chunk, batch) ----
// Chunk c>0 starts from alpha=1 and runs WARM unaccounted steps (forced
// renorm at the last warm-up step), then CHL tracked steps. Chunk loglik
// contributions atomicAdd into out[b]. areg pinned in VGPRs via asm.
__global__ __launch_bounds__(960) __attribute__((amdgpu_waves_per_eu(4, 4)))
void hmm_forward(const uint32_t* __restrict__ Apack,
                 const uint32_t* __restrict__ emisPack,
                 const float* __restrict__ Ivec,
                 float* __restrict__ out) {
  __shared__ alignas(16) uint32_t alphaPair[NPAIR];
  __shared__ float part[NC * S_PAD];
  __shared__ uint32_t eBuf[2][NPAIR];
  __shared__ float zslot[8];
  int chunk = blockIdx.x;        // 0..NCHUNK-1
  int b = blockIdx.y;            // 0..NBATCH-1
  int tid = threadIdx.x;
  int j = tid % S_PAD, cc = tid / S_PAD;

  // load A fragment into registers (coalesced in j), then pin in VGPRs
  uint32_t areg[PPC];
  {
    const uint32_t* ap = Apack + (size_t)cc * PPC * S_PAD + j;
#pragma unroll
    for (int p2 = 0; p2 < PPC; p2++) areg[p2] = ap[p2 * S_PAD];
  }
#pragma unroll
  for (int p2 = 0; p2 < PPC; p2++) asm volatile("" : "+v"(areg[p2]));

  const uint32_t* eb = emisPack + (size_t)b * T_LEN * NPAIR;

  int tbase = chunk * CHL;                  // first accounted step
  int tend = tbase + CHL - 1;               // last accounted step
  int t0;                                   // first loop step

  if (chunk == 0) {
    t0 = 1;
    // t = 0: stored = I * e0 * 128
    if (cc == 0) {
      float Ij = (j < S_DIM) ? Ivec[j] : 0.f;
      U32H2 ue; ue.u = eb[j >> 1];
      float e0 = (j & 1) ? (float)ue.h.y : (float)ue.h.x;
      ((_Float16*)alphaPair)[j] = (_Float16)(Ij * e0 * 128.f);
    }
  } else {
    t0 = tbase - WARM;
    if (cc == 0) ((_Float16*)alphaPair)[j] = (_Float16)((j < S_DIM) ? 1.f : 0.f);
  }

  // emission double-buffer prefetch (cc==2 group owns it)
  uint32_t ev = 0;
  if (cc == 2 && j < NPAIR) {
    eBuf[t0 & 1][j] = eb[(size_t)t0 * NPAIR + j];
    int t1 = t0 + 1; if (t1 > tend) t1 = tend;
    ev = eb[(size_t)t1 * NPAIR + j];
  }
  float ll = 0.f;
  __syncthreads();

  for (int t = t0; t <= tend; t++) {
    // rolling emission prefetch: publish t+1 (already in reg), issue t+2
    if (cc == 2 && j < NPAIR) {
      eBuf[(t + 1) & 1][j] = ev;
      int tn = t + 2; if (tn > tend) tn = tend;
      ev = eb[(size_t)tn * NPAIR + j];
    }
    // partial dot: acc = sum over this thread's k-chunk of alpha[k]*A[k][j]
    float acc = 0.f;
    const uint4* apv = (const uint4*)(alphaPair + cc * PPC);
#pragma unroll
    for (int i = 0; i < 13; i++) {
      uint4 q = apv[i];
      acc = fdot2u(areg[4 * i + 0], q.x, acc);
      acc = fdot2u(areg[4 * i + 1], q.y, acc);
      acc = fdot2u(areg[4 * i + 2], q.z, acc);
      acc = fdot2u(areg[4 * i + 3], q.w, acc);
    }
    part[cc * S_PAD + j] = acc;
    bool renorm = ((t & 7) == 0) || (t == tend) || (t == tbase - 1);
    __syncthreads();

    float s = 0.f;
    if (cc == 0) {
      s = part[j] + part[S_PAD + j] + part[2 * S_PAD + j];
      _Float16 ehv = ((_Float16*)(eBuf[t & 1]))[j];   // 0 for pad j
      s = s * (float)ehv * 128.f;
      if (renorm) {
        float w = s;
#pragma unroll
        for (int off = 32; off >= 1; off >>= 1) w += __shfl_xor(w, off);
        if ((j & 63) == 0) zslot[j >> 6] = w;
      }
    }
    if (renorm) {
      __syncthreads();
      if (cc == 0) {
        float m = zslot[0] + zslot[1] + zslot[2] + zslot[3] + zslot[4];
        if (tid == 0 && t >= tbase) ll += logf(m);   // warm-up renorms untracked
        s /= m;
      }
    }
    if (cc == 0) ((_Float16*)alphaPair)[j] = (_Float16)s;
    __syncthreads();
  }
  // per-chunk: ll - CHL*ln(128). Sum over 8 chunks = total - 4096*ln(128).
  if (tid == 0) atomicAdd(&out[b], ll - 2484.23949510f);
}

extern "C" void kernel_launch(void* const* d_in, const int* in_sizes, int n_in,
                              void* d_out, int out_size, void* d_ws, size_t ws_size,
                              hipStream_t stream) {
  const float* inp = (const float*)d_in[0];   // [32,4096,126]
  const float* A   = (const float*)d_in[1];   // [308,308]
  const float* Bm  = (const float*)d_in[2];   // [308,126]
  const float* Iv  = (const float*)d_in[3];   // [308]
  float* out = (float*)d_out;                 // [32]

  uint8_t* ws = (uint8_t*)d_ws;
  uint32_t* Apack    = (uint32_t*)(ws);                 // 156*320*4   = 199,680 B
  float*    Bt       = (float*)(ws + (256u << 10));     // 126*320*4   = 161,280 B
  uint32_t* emisPack = (uint32_t*)(ws + (512u << 10));  // 32*4096*160*4 = 83,886,080 B

  hipLaunchKernelGGL(zero_out,    dim3(1),        dim3(64),  0, stream, out);
  hipLaunchKernelGGL(pack_A,      dim3(NC * PPC), dim3(320), 0, stream, A, Apack);
  hipLaunchKernelGGL(transpose_B, dim3(E_DIM),    dim3(320), 0, stream, Bm, Bt);
  hipLaunchKernelGGL(emis_kernel, dim3(NBATCH, T_LEN / 32), dim3(320), 0, stream, inp, Bt, emisPack);
  hipLaunchKernelGGL(hmm_forward, dim3(NCHUNK, NBATCH), dim3(960), 0, stream, Apack, emisPack, Iv, out);
}